// Round 16
// baseline (112.807 us; speedup 1.0000x reference)
//
#include <hip/hip_runtime.h>
#include <math.h>

#define NH 8
#define NKV 2
#define SEGL 1024
#define NSEG 8
#define NTOK 8192
#define BATCH 2
#define DIMK 512

typedef short short8v __attribute__((ext_vector_type(8)));
typedef short short4v __attribute__((ext_vector_type(4)));
typedef float f32x4 __attribute__((ext_vector_type(4)));
typedef int int4v __attribute__((ext_vector_type(4)));

#define MFMA16 __builtin_amdgcn_mfma_f32_16x16x32_bf16

__device__ __forceinline__ unsigned short f2bf(float f) {
  union { float f; unsigned u; } c; c.f = f;
  unsigned u = c.u;
  return (unsigned short)((u + 0x7FFFu + ((u >> 16) & 1u)) >> 16);
}
__device__ __forceinline__ float bf2f(unsigned short h) {
  union { unsigned u; float f; } c; c.u = ((unsigned)h) << 16;
  return c.f;
}
// HW packed f32->bf16 (RNE, identical to f2bf emulation). T12 primitive.
__device__ __forceinline__ unsigned cvtpk(float lo, float hi) {
  unsigned r;
  asm("v_cvt_pk_bf16_f32 %0, %1, %2" : "=v"(r) : "v"(lo), "v"(hi));
  return r;
}

// async global->LDS, 16 bytes per lane. LDS dest must be wave-uniform + lane*16.
__device__ __forceinline__ void gload16(const unsigned short* g, unsigned short* l) {
  __builtin_amdgcn_global_load_lds(
      (const __attribute__((address_space(1))) unsigned int*)g,
      (__attribute__((address_space(3))) unsigned int*)l, 16, 0, 0);
}

// ---------------------------------------------------------------------------
// f32 -> bf16 cast; y selects input (0 = a, 1 = x).
// ---------------------------------------------------------------------------
__global__ void cast_bf16_kernel(const float* __restrict__ a, const float* __restrict__ x,
                                 unsigned short* __restrict__ outa,
                                 unsigned short* __restrict__ outx) {
  const float* in = blockIdx.y ? x : a;
  unsigned short* out = blockIdx.y ? outx : outa;
  int i = blockIdx.x * blockDim.x + threadIdx.x;
  const float4* p = (const float4*)in + (size_t)i * 2;
  float4 v0 = p[0], v1 = p[1];
  short8v o;
  o[0] = (short)f2bf(v0.x); o[1] = (short)f2bf(v0.y);
  o[2] = (short)f2bf(v0.z); o[3] = (short)f2bf(v0.w);
  o[4] = (short)f2bf(v1.x); o[5] = (short)f2bf(v1.y);
  o[6] = (short)f2bf(v1.z); o[7] = (short)f2bf(v1.w);
  *((short8v*)out + i) = o;
}

// ---------------------------------------------------------------------------
// W (512 x C) f32 -> Wt (C x 512) bf16; z in 0..5 selects the weight.
// z == 6: fill RoPE cos/sin table.
// ---------------------------------------------------------------------------
__global__ void wtrans_kernel(const float* __restrict__ w0, const float* __restrict__ w1,
                              const float* __restrict__ w2, const float* __restrict__ w3,
                              const float* __restrict__ w4, const float* __restrict__ w5,
                              unsigned short* __restrict__ o0, unsigned short* __restrict__ o1,
                              unsigned short* __restrict__ o2, unsigned short* __restrict__ o3,
                              unsigned short* __restrict__ o4, unsigned short* __restrict__ o5,
                              float* __restrict__ rtab) {
  __shared__ float T[32][33];
  const int z = blockIdx.z;
  if (z == 6) {
    const int flat = blockIdx.y * 16 + blockIdx.x;       // 0..255
    const int base = (flat * 256 + threadIdx.x) * 8;     // covers 524288
    const float LOG1E4 = 9.210340371976184f;
    #pragma unroll
    for (int k = 0; k < 8; k++) {
      int e = base + k;
      int pos = e >> 6, c = e & 63, jj = c & 31;
      float inv = __expf(-((float)jj / 32.f) * LOG1E4);
      float sn, cs;
      sincosf((float)pos * inv, &sn, &cs);
      rtab[e] = (c < 32) ? cs : sn;
    }
    return;
  }
  const float* in; unsigned short* out; int C;
  switch (z) {
    case 0: in = w0; out = o0; C = 512; break;
    case 1: in = w1; out = o1; C = 128; break;
    case 2: in = w2; out = o2; C = 128; break;
    case 3: in = w3; out = o3; C = 512; break;
    case 4: in = w4; out = o4; C = 128; break;
    default: in = w5; out = o5; C = 128; break;
  }
  const int c0 = blockIdx.x * 32, k0 = blockIdx.y * 32;
  if (c0 >= C) return;
  const int tx = threadIdx.x & 31, ty = threadIdx.x >> 5;
  #pragma unroll
  for (int i = 0; i < 4; i++)
    T[ty + i * 8][tx] = in[(size_t)(k0 + ty + i * 8) * C + c0 + tx];
  __syncthreads();
  #pragma unroll
  for (int i = 0; i < 4; i++)
    out[(size_t)(c0 + ty + i * 8) * 512 + k0 + tx] = f2bf(T[tx][ty + i * 8]);
}

// ---------------------------------------------------------------------------
// Merged MFMA projection v3: 128-row x 64-col block, double-buffered
// global_load_lds staging, XOR-granule swizzle, BK=64, 8 k-steps.
// grid (64, 12, 2).
// ---------------------------------------------------------------------------
__global__ __launch_bounds__(256, 3) void proj_all_kernel(
    const unsigned short* __restrict__ Xa, const unsigned short* __restrict__ Xx,
    const unsigned short* __restrict__ WtQa, const unsigned short* __restrict__ WtKa,
    const unsigned short* __restrict__ WtVa, const unsigned short* __restrict__ WtQx,
    const unsigned short* __restrict__ WtKx, const unsigned short* __restrict__ WtVx,
    const float* __restrict__ gq_a, const float* __restrict__ gk_a,
    const float* __restrict__ gq_x, const float* __restrict__ gk_x,
    const float* __restrict__ Rtab,
    unsigned short* __restrict__ Qb, unsigned short* __restrict__ Kb,
    unsigned short* __restrict__ Kt, unsigned short* __restrict__ Vt)
{
  __shared__ __attribute__((aligned(16))) unsigned short Xs[2][128][64];  // 32 KB
  __shared__ __attribute__((aligned(16))) unsigned short Ws2[2][64][64];  // 16 KB
  unsigned short (*Tsh)[72] = (unsigned short (*)[72])&Xs[0][0][0];       // alias

  const int tid = threadIdx.x;
  const int w = tid >> 6, l = tid & 63, lc = l & 15, lg = l >> 4;
  const int r7 = lc & 7;
  const int z = blockIdx.z;
  const int y = blockIdx.y;
  const int row0 = blockIdx.x * 128;
  const int pos_offset = z ? 4096 : 0;

  const unsigned short* Xbf = z ? Xx : Xa;
  const unsigned short* Wt;
  const float* gamma = nullptr;
  unsigned short* OUT = nullptr;
  unsigned short* OUTT = nullptr;
  int h, Hout, doNR;
  if (y < 8) {
    h = y; Hout = NH; doNR = 1;
    Wt = z ? WtQx : WtQa; gamma = z ? gq_x : gq_a; OUT = Qb;
  } else if (y < 10) {
    h = y - 8; Hout = NKV; doNR = 1;
    Wt = z ? WtKx : WtKa; gamma = z ? gk_x : gk_a; OUT = Kb; OUTT = Kt;
  } else {
    h = y - 10; Hout = NKV; doNR = 0;
    Wt = z ? WtVx : WtVa; OUTT = Vt;
  }

  const int srow = tid >> 3;
  const int sg   = (tid & 7) ^ (srow & 7);
  const unsigned short* Xrow = Xbf + (size_t)(row0 + srow) * 512 + sg * 8;
  const unsigned short* Wrow = Wt + (size_t)(h * 64 + srow) * 512 + sg * 8;

  f32x4 acc[2][4];
  #pragma unroll
  for (int m = 0; m < 2; m++)
    #pragma unroll
    for (int ct = 0; ct < 4; ct++) { acc[m][ct][0]=0.f; acc[m][ct][1]=0.f; acc[m][ct][2]=0.f; acc[m][ct][3]=0.f; }

  // ---- prologue: stage k-step 0 into buf 0 ----
  #pragma unroll
  for (int p = 0; p < 4; p++)
    gload16(Xrow + (size_t)p * 32 * 512, &Xs[0][0][0] + p * 2048 + tid * 8);
  #pragma unroll
  for (int p = 0; p < 2; p++)
    gload16(Wrow + (size_t)p * 32 * 512, &Ws2[0][0][0] + p * 2048 + tid * 8);
  __syncthreads();

  for (int s = 0; s < 8; s++) {
    const int buf = s & 1;
    if (s < 7) {
      const int k0n = (s + 1) * 64;
      #pragma unroll
      for (int p = 0; p < 4; p++)
        gload16(Xrow + (size_t)p * 32 * 512 + k0n, &Xs[buf ^ 1][0][0] + p * 2048 + tid * 8);
      #pragma unroll
      for (int p = 0; p < 2; p++)
        gload16(Wrow + (size_t)p * 32 * 512 + k0n, &Ws2[buf ^ 1][0][0] + p * 2048 + tid * 8);
    }

    __builtin_amdgcn_s_setprio(1);
    #pragma unroll
    for (int kc = 0; kc < 2; kc++) {
      const int gsw = (((kc * 4 + lg) ^ r7) & 7) * 8;
      short8v a8[2], b8[4];
      #pragma unroll
      for (int m = 0; m < 2; m++)
        a8[m] = *(const short8v*)&Xs[buf][m * 64 + w * 16 + lc][gsw];
      #pragma unroll
      for (int ct = 0; ct < 4; ct++)
        b8[ct] = *(const short8v*)&Ws2[buf][ct * 16 + lc][gsw];
      #pragma unroll
      for (int m = 0; m < 2; m++)
        #pragma unroll
        for (int ct = 0; ct < 4; ct++)
          acc[m][ct] = MFMA16(a8[m], b8[ct], acc[m][ct], 0, 0, 0);
    }
    __builtin_amdgcn_s_setprio(0);
    __syncthreads();
  }

  // ---- epilogue ----
  float gam[4];
  if (doNR) {
    #pragma unroll
    for (int ct = 0; ct < 4; ct++) gam[ct] = gamma[h * 64 + ct * 16 + lc];
  }

  #pragma unroll
  for (int m = 0; m < 2; m++) {
    if (doNR) {
      float srw[4];
      #pragma unroll
      for (int reg = 0; reg < 4; reg++) {
        float ss = acc[m][0][reg]*acc[m][0][reg] + acc[m][1][reg]*acc[m][1][reg]
                 + acc[m][2][reg]*acc[m][2][reg] + acc[m][3][reg]*acc[m][3][reg];
        ss += __shfl_xor(ss, 1, 64);
        ss += __shfl_xor(ss, 2, 64);
        ss += __shfl_xor(ss, 4, 64);
        ss += __shfl_xor(ss, 8, 64);
        srw[reg] = 8.0f / fmaxf(sqrtf(ss), 1e-12f);
      }
      const int posb = pos_offset + ((row0 + m * 64) & 4095) + w * 16 + lg * 4;
      #pragma unroll
      for (int reg = 0; reg < 4; reg++) {
        const float* tabr = Rtab + (size_t)(posb + reg) * 64;
        #pragma unroll
        for (int half = 0; half < 2; half++) {
          float cs = tabr[half * 16 + lc];
          float sn = tabr[32 + half * 16 + lc];
          float v1 = acc[m][half][reg] * srw[reg] * gam[half];
          float v2 = acc[m][half + 2][reg] * srw[reg] * gam[half + 2];
          acc[m][half][reg]     = v1 * cs - v2 * sn;
          acc[m][half + 2][reg] = v2 * cs + v1 * sn;
        }
      }
    }

    #pragma unroll
    for (int ct = 0; ct < 4; ct++)
      #pragma unroll
      for (int reg = 0; reg < 4; reg++)
        Tsh[w * 16 + lg * 4 + reg][ct * 16 + lc] = f2bf(acc[m][ct][reg]);
    __syncthreads();

    const int growm = row0 + m * 64;
    const int b = growm >> 12;
    const int pos0 = pos_offset + (growm & 4095);
    if (OUT) {
      const int r = tid >> 2, part = tid & 3;
      unsigned short* dst = OUT + (((size_t)b * Hout + h) * NTOK + pos0 + r) * 64 + part * 16;
      short8v u0 = *(const short8v*)&Tsh[r][part * 16];
      short8v u1 = *(const short8v*)&Tsh[r][part * 16 + 8];
      *(short8v*)dst = u0;
      *(short8v*)(dst + 8) = u1;
    }
    if (OUTT) {
      const int e = tid >> 2, part = tid & 3;
      short8v t0, t1;
      #pragma unroll
      for (int jj = 0; jj < 16; jj++) {
        const int LG = ((part & 1) << 1) | (jj >> 3);
        const int H  = (jj >> 2) & 1;
        const int I  = jj & 3;
        const int srcrow = (part >> 1) * 32 + H * 16 + LG * 4 + I;
        unsigned short v = Tsh[srcrow][e];
        if (jj < 8) t0[jj] = (short)v; else t1[jj - 8] = (short)v;
      }
      unsigned short* dstT = OUTT + (((size_t)b * NKV + h) * 64 + e) * NTOK + pos0 + part * 16;
      *(short8v*)dstT = t0;
      *(short8v*)(dstT + 8) = t1;
    }
    __syncthreads();
  }
}

// ---------------------------------------------------------------------------
// Per-segment partial summaries (8 n-chunks of 128 tokens) via MFMA.
// grid 256 = (bkv*8+seg)*8+chunk.
// ---------------------------------------------------------------------------
__global__ __launch_bounds__(256) void seg_summary_kernel(
    const unsigned short* __restrict__ Kt, const unsigned short* __restrict__ Vt,
    float* __restrict__ Spart, float* __restrict__ Zpart)
{
  const int blk = blockIdx.x;
  const int chunk = blk & 7;
  const int seg = (blk >> 3) & 7;
  const int bkv = blk >> 6;
  const int tid = threadIdx.x;
  const int w = tid >> 6, l = tid & 63, lc = l & 15, lg = l >> 4;
  const unsigned short* KtB = Kt + ((size_t)bkv * 64) * NTOK + seg * SEGL + chunk * 128;
  const unsigned short* VtB = Vt + ((size_t)bkv * 64) * NTOK + seg * SEGL + chunk * 128;

  f32x4 acc[4];
  #pragma unroll
  for (int ct = 0; ct < 4; ct++) { acc[ct][0]=0.f; acc[ct][1]=0.f; acc[ct][2]=0.f; acc[ct][3]=0.f; }
  float zacc[4] = {0.f, 0.f, 0.f, 0.f};

  for (int n0 = 0; n0 < 128; n0 += 32) {
    short8v av = *(const short8v*)(VtB + (size_t)(w * 16 + lc) * NTOK + n0 + lg * 8);
    #pragma unroll
    for (int ct = 0; ct < 4; ct++) {
      short8v kv = *(const short8v*)(KtB + (size_t)(ct * 16 + lc) * NTOK + n0 + lg * 8);
      short8v skv;
      float zp = 0.f;
      #pragma unroll
      for (int i = 0; i < 8; i++) {
        float kf = bf2f((unsigned short)kv[i]);
        float sk = kf > 0.f ? kf + 1.f : __expf(kf);
        zp += sk;
        skv[i] = (short)f2bf(sk);
      }
      zacc[ct] += zp;
      acc[ct] = MFMA16(av, skv, acc[ct], 0, 0, 0);
    }
  }

  float* Sp = Spart + (size_t)blk * 4096;
  #pragma unroll
  for (int ct = 0; ct < 4; ct++)
    #pragma unroll
    for (int reg = 0; reg < 4; reg++)
      Sp[(size_t)(w * 16 + lg * 4 + reg) * 64 + ct * 16 + lc] = acc[ct][reg];

  if (w == 0) {
    #pragma unroll
    for (int ct = 0; ct < 4; ct++) {
      zacc[ct] += __shfl_xor(zacc[ct], 16, 64);
      zacc[ct] += __shfl_xor(zacc[ct], 32, 64);
    }
    if (lg == 0) {
      float* Zp = Zpart + (size_t)blk * 64;
      #pragma unroll
      for (int ct = 0; ct < 4; ct++) Zp[ct * 16 + lc] = zacc[ct];
    }
  }
}

// Chunk-reduce + exclusive prefix over segments -> bf16 PT + f32 PZ.
__global__ void prefix_kernel(const float* __restrict__ Spart, const float* __restrict__ Zpart,
                              unsigned short* __restrict__ PT, float* __restrict__ PZ)
{
  const int bkv = blockIdx.x;
  const int col = blockIdx.y * 256 + threadIdx.x;
  float run = 0.f;
  for (int s = 0; s < NSEG; s++) {
    float v = 0.f;
    #pragma unroll
    for (int c = 0; c < 8; c++)
      v += Spart[(((size_t)(bkv * 8 + s)) * 8 + c) * 4096 + col];
    PT[((size_t)bkv * 8 + s) * 4096 + col] = f2bf(run);
    run += v;
  }
  if (blockIdx.y == 0 && threadIdx.x < 64) {
    const int d = threadIdx.x;
    float rz = 0.f;
    for (int s = 0; s < NSEG; s++) {
      float v = 0.f;
      #pragma unroll
      for (int c = 0; c < 8; c++)
        v += Zpart[(((size_t)(bkv * 8 + s)) * 8 + c) * 64 + d];
      PZ[((size_t)bkv * 8 + s) * 64 + d] = rz;
      rz += v;
    }
  }
}

// ---------------------------------------------------------------------------
// MFMA flash attention v11: single q-tile per block, 2 heads sharing staged
// K/V (R12 compute body verbatim), grid 1024 = (b,kv,p,seg,qt) -> 4 blocks/CU
// all co-resident. Staging schedule = R9/R12-exact. XCD chunk = one (b,kv,p).
// ---------------------------------------------------------------------------
__global__ __launch_bounds__(256, 4) void attn_mfma_kernel(
    const unsigned short* __restrict__ Qb, const unsigned short* __restrict__ Kb,
    const unsigned short* __restrict__ Vt, const unsigned short* __restrict__ PT,
    const float* __restrict__ PZ, const float* __restrict__ beta,
    float* __restrict__ OUT)
{
  __shared__ __attribute__((aligned(16))) unsigned short Ks[2][64][64];
  __shared__ __attribute__((aligned(16))) unsigned short Vs[2][64][64];
  const int tid = threadIdx.x;
  const int w = tid >> 6;
  const int l = tid & 63;
  const int lc = l & 15;
  const int lg = l >> 4;
  const int r7 = lc & 7;

  // XCD-aware bijective swizzle (1024 blocks = 8 x 128): each XCD chunk
  // covers one (b,kv,p) -> its 2 MB K/V set stays in the XCD-private L2.
  const int bid = (blockIdx.x & 7) * 128 + (blockIdx.x >> 3);
  const int qt  = bid & 15;
  const int seg = (bid >> 4) & 7;
  const int pp  = (bid >> 7) & 1;
  const int kv  = (bid >> 8) & 1;
  const int b   = bid >> 9;
  const int bkv = b * NKV + kv;          // jnp.tile -> h % KVH
  const int segbase = seg * SEGL;

  const unsigned short* Kbase = Kb + ((size_t)bkv * NTOK + segbase) * 64;
  const unsigned short* Vbase = Vt + ((size_t)bkv * 64) * NTOK + segbase;

  // staging constants: identical to proven R9/R12 schedule
  const int srow = tid >> 3;                 // 0..31
  const int sg   = (tid & 7) ^ (srow & 7);   // involution granule swizzle

  // Q fragments: [hh] for this block's single q-tile
  short8v aq0[2], aq1[2];
  #pragma unroll
  for (int hh = 0; hh < 2; hh++) {
    const int h = kv + 4 * pp + 2 * hh;
    const int bh = b * NH + h;
    const unsigned short* qp =
        Qb + (((size_t)bh * NTOK) + segbase + qt * 64 + w * 16 + lc) * 64 + lg * 8;
    aq0[hh] = *(const short8v*)(qp);
    aq1[hh] = *(const short8v*)(qp + 32);
  }

  f32x4 O[2][4];
  #pragma unroll
  for (int hh = 0; hh < 2; hh++)
    #pragma unroll
    for (int ce = 0; ce < 4; ce++) { O[hh][ce][0]=0.f; O[hh][ce][1]=0.f; O[hh][ce][2]=0.f; O[hh][ce][3]=0.f; }
  float rsumL[2] = {0.f, 0.f};

  // exp(s*0.125 - 8) == exp2(s*c1 - c2)
  const float c1 = 0.125f * 1.44269504089f;
  const float c2 = 8.0f * 1.44269504089f;

  // ---- prologue: stage tile 0 (R9/R12-exact) ----
  {
    unsigned short* kD = &Ks[0][0][0];
    unsigned short* vD = &Vs[0][0][0];
    #pragma unroll
    for (int p = 0; p < 2; p++) {
      const int row = p * 32 + srow;
      gload16(Kbase + (size_t)row * 64 + sg * 8, kD + p * 2048 + tid * 8);
      gload16(Vbase + (size_t)row * NTOK + sg * 8, vD + p * 2048 + tid * 8);
    }
  }
  __syncthreads();

  for (int kt = 0; kt <= qt; ++kt) {
    const int buf = kt & 1;
    if (kt < qt) {
      const int ktn = kt + 1;
      unsigned short* kD = &Ks[buf ^ 1][0][0];
      unsigned short* vD = &Vs[buf ^ 1][0][0];
      #pragma unroll
      for (int p = 0; p < 2; p++) {
        const int row = p * 32 + srow;
        gload16(Kbase + (size_t)(ktn * 64 + row) * 64 + sg * 8, kD + p * 2048 + tid * 8);
        gload16(Vbase + (size_t)row * NTOK + ktn * 64 + sg * 8, vD + p * 2048 + tid * 8);
      }
    }

    __builtin_amdgcn_s_setprio(1);

    // ---- hoisted per-step K/V fragment reads (shared by both heads) ----
    short8v ak0r[4], ak1r[4];
    #pragma unroll
    for (int ck = 0; ck < 4; ck++) {
      const int krow = ck * 16 + lc;
      ak0r[ck] = *(const short8v*)&Ks[buf][krow][((lg ^ r7) & 7) * 8];
      ak1r[ck] = *(const short8v*)&Ks[buf][krow][(((lg + 4) ^ r7) & 7) * 8];
    }
    short8v bvr[2][4];
    #pragma unroll
    for (int cp = 0; cp < 2; cp++)
      #pragma unroll
      for (int ce = 0; ce < 4; ce++)
        bvr[cp][ce] = *(const short8v*)&Vs[buf][ce * 16 + lc][(((cp * 4 + lg) ^ r7) & 7) * 8];

    const bool diag = (kt == qt);
    const int ctmax = diag ? w : 3;

    #pragma unroll
    for (int hh = 0; hh < 2; hh++) {
      // ---- S^T = K Q^T, P = exp2(s*c1 - c2) with causal mask ----
      unsigned paw[4][2];
      #pragma unroll
      for (int ck = 0; ck < 4; ck++) {
        if (ck > ctmax) { paw[ck][0] = 0u; paw[ck][1] = 0u; continue; }
        f32x4 s;
        s[0]=0.f; s[1]=0.f; s[2]=0.f; s[3]=0.f;
        s = MFMA16(ak0r[ck], aq0[hh], s, 0, 0, 0);
        s = MFMA16(ak1r[ck], aq1[hh], s, 0, 0, 0);
        const bool needmask = diag && (ck == w);
        float p0 = exp2f(s[0] * c1 - c2);
        float p1 = exp2f(s[1] * c1 - c2);
        float p2 = exp2f(s[2] * c1 - c2);
        float p3 = exp2f(s[3] * c1 - c2);
        if (needmask) {
          if (lg * 4 + 0 > lc) p0 = 0.f;
          if (lg * 4 + 1 > lc) p1 = 0.f;
          if (lg * 4 + 2 > lc) p2 = 0.f;
          if (lg * 4 + 3 > lc) p3 = 0.f;
        }
        rsumL[hh] += p0 + p1 + p2 + p3;
        paw[ck][0] = cvtpk(p0, p1);
        paw[ck][1] = cvtpk(p2, p3);
      }

      // ---- O += P V via 16x16x32; A from packed words, B from registers ----
      #pragma unroll
      for (int cp = 0; cp < 2; cp++) {
        if (cp * 2 > ctmax) continue;
        int4v a8i;
        a8i[0] = (int)paw[cp * 2][0];
        a8i[1] = (int)paw[cp * 2][1];
        a8i[2] = (int)paw[cp * 2 + 1][0];
        a8i[3] = (int)paw[cp * 2 + 1][1];
        short8v a8;
        __builtin_memcpy(&a8, &a8i, 16);
        #pragma unroll
        for (int ce = 0; ce < 4; ce++)
          O[hh][ce] = MFMA16(a8, bvr[cp][ce], O[hh][ce], 0, 0, 0);
      }
    }
    __builtin_amdgcn_s_setprio(0);
    __syncthreads();
  }

  // ---- epilogue per head: softmax sum + memory path + gated write ----
  const unsigned short* stp = PT + ((size_t)bkv * NSEG + seg) * 4096 + lc * 64 + lg * 8;
  const float* zp = PZ + ((size_t)bkv * NSEG + seg) * 64 + lg * 8;

  #pragma unroll
  for (int hh = 0; hh < 2; hh++) {
    const int h = kv + 4 * pp + 2 * hh;
    const float g = 1.f / (1.f + __expf(-beta[h]));
    const float g1 = 1.f - g;

    float rsum = rsumL[hh];
    rsum += __shfl_xor(rsum, 16, 64);
    rsum += __shfl_xor(rsum, 32, 64);

    float sq0[8], sq1[8];
    float den = 1e-12f;
    #pragma unroll
    for (int i = 0; i < 8; i++) {
      float f0 = bf2f((unsigned short)aq0[hh][i]);
      sq0[i] = f0 > 0.f ? f0 + 1.f : __expf(f0);
      den += sq0[i] * zp[i];
      float f1 = bf2f((unsigned short)aq1[hh][i]);
      sq1[i] = f1 > 0.f ? f1 + 1.f : __expf(f1);
      den += sq1[i] * zp[32 + i];
    }
    int4v q0i, q1i;
    q0i[0] = (int)cvtpk(sq0[0], sq0[1]);
    q0i[1] = (int)cvtpk(sq0[2], sq0[3]);
    q0i[2] = (int)cvtpk(sq0[4], sq0[5]);
    q0i[3] = (int)cvtpk(sq0[6], sq0[7]);
    q1i[0] = (int)cvtpk(sq1[0], sq1[1]);
    q1i[1] = (int)cvtpk(sq1[2], sq1[3]);
    q1i[2] = (int)cvtpk(sq1[4], sq1[5]);
    q1i[3] = (int)cvtpk(sq1[6], sq1[7]);
    short8v asq0, asq1;
    __builtin_memcpy(&asq0, &q0i, 16);
    __builtin_memcpy(&asq1, &q1i, 16);

    f32x4 N[4];
    #pragma unroll
    for (int ct = 0; ct < 4; ct++) { N[ct][0]=0.f; N[ct][1]=0.f; N[ct][2]=0.f; N[ct][3]=0.f; }
    #pragma unroll
    for (int ct = 0; ct < 4; ct++) {
      short8v bs0 = *(const short8v*)(stp + ct * 16 * 64);
      short8v bs1 = *(const short8v*)(stp + ct * 16 * 64 + 32);
      N[ct] = MFMA16(asq0, bs0, N[ct], 0, 0, 0);
      N[ct] = MFMA16(asq1, bs1, N[ct], 0, 0, 0);
    }
    den += __shfl_xor(den, 16, 64);
    den += __shfl_xor(den, 32, 64);
    float denc[4], rs[4];
    #pragma unroll
    for (int reg = 0; reg < 4; reg++) {
      denc[reg] = __shfl(den, lg * 4 + reg, 64);
      rs[reg]   = __shfl(rsum, lg * 4 + reg, 64);
    }

    const int nrow = segbase + qt * 64 + w * 16 + lg * 4;
    #pragma unroll
    for (int reg = 0; reg < 4; reg++) {
      const int n = nrow + reg;
      const float invs = 1.f / rs[reg];
      const float invd = 1.f / denc[reg];
      size_t obase;
      if (n < 4096) obase = (size_t)BATCH * 4096 * 512 + (((size_t)b * 4096 + n) * NH + h) * 64;
      else          obase = (((size_t)b * 4096 + (n - 4096)) * NH + h) * 64;
      #pragma unroll
      for (int ce = 0; ce < 4; ce++) {
        OUT[obase + ce * 16 + lc] = g * N[ce][reg] * invd + g1 * O[hh][ce][reg] * invs;
      }
    }
  }
}

// ---------------------------------------------------------------------------
extern "C" void kernel_launch(void* const* d_in, const int* in_sizes, int n_in,
                              void* d_out, int out_size, void* d_ws, size_t ws_size,
                              hipStream_t stream) {
  const float* x    = (const float*)d_in[0];
  const float* a    = (const float*)d_in[1];
  const float* Wq_x = (const float*)d_in[2];
  const float* Wk_x = (const float*)d_in[3];
  const float* Wv_x = (const float*)d_in[4];
  const float* Wq_a = (const float*)d_in[5];
  const float* Wk_a = (const float*)d_in[6];
  const float* Wv_a = (const float*)d_in[7];
  const float* gq_x = (const float*)d_in[8];
  const float* gk_x = (const float*)d_in[9];
  const float* gq_a = (const float*)d_in[10];
  const float* gk_a = (const float*)d_in[11];
  const float* beta = (const float*)d_in[12];

  unsigned short* Qb = (unsigned short*)d_ws;          // 8388608
  unsigned short* Kb = Qb + (size_t)8388608;           // 2097152
  unsigned short* Kt = Kb + (size_t)2097152;           // 2097152 (permuted)
  unsigned short* Vt = Kt + (size_t)2097152;           // 2097152 (permuted)
  unsigned short* Xa = Vt + (size_t)2097152;           // 4194304
  unsigned short* Xx = Xa + (size_t)4194304;           // 4194304
  unsigned short* WtQa = Xx + (size_t)4194304;         // 262144
  unsigned short* WtKa = WtQa + (size_t)262144;        // 65536
  unsigned short* WtVa = WtKa + (size_t)65536;         // 65536
  unsigned short* WtQx = WtVa + (size_t)65536;         // 262144
  unsigned short* WtKx = WtQx + (size_t)262144;        // 65536
  unsigned short* WtVx = WtKx + (size_t)65536;         // 65536
  float* Spart = (float*)(WtVx + (size_t)65536);       // 1048576 f32 (4 MB)
  float* Zpart = Spart + (size_t)1048576;              // 16384
  float* PZ = Zpart + (size_t)16384;                   // 2048
  unsigned short* PT = (unsigned short*)(PZ + (size_t)2048); // 131072 bf16
  float* Rtab = (float*)(PT + (size_t)131072);         // 524288 f32 (2 MB)

  cast_bf16_kernel<<<dim3(2048, 2), 256, 0, stream>>>(a, x, Xa, Xx);
  wtrans_kernel<<<dim3(16, 16, 7), 256, 0, stream>>>(
      Wq_a, Wk_a, Wv_a, Wq_x, Wk_x, Wv_x, WtQa, WtKa, WtVa, WtQx, WtKx, WtVx, Rtab);
  proj_all_kernel<<<dim3(64, 12, 2), 256, 0, stream>>>(
      Xa, Xx, WtQa, WtKa, WtVa, WtQx, WtKx, WtVx,
      gq_a, gk_a, gq_x, gk_x, Rtab, Qb, Kb, Kt, Vt);
  seg_summary_kernel<<<256, 256, 0, stream>>>(Kt, Vt, Spart, Zpart);
  prefix_kernel<<<dim3(4, 16), 256, 0, stream>>>(Spart, Zpart, PT, PZ);
  attn_mfma_kernel<<<dim3(1024), 256, 0, stream>>>(Qb, Kb, Vt, PT, PZ, beta, (float*)d_out);
}

// Round 17
// 92.648 us; speedup vs baseline: 1.2176x; 1.2176x over previous
//
#include <hip/hip_runtime.h>
#include <math.h>

#define NH 8
#define NKV 2
#define SEGL 1024
#define NSEG 8
#define NTOK 8192
#define BATCH 2
#define DIMK 512

typedef short short8v __attribute__((ext_vector_type(8)));
typedef short short4v __attribute__((ext_vector_type(4)));
typedef float f32x4 __attribute__((ext_vector_type(4)));
typedef int int4v __attribute__((ext_vector_type(4)));

#define MFMA16 __builtin_amdgcn_mfma_f32_16x16x32_bf16

__device__ __forceinline__ unsigned short f2bf(float f) {
  union { float f; unsigned u; } c; c.f = f;
  unsigned u = c.u;
  return (unsigned short)((u + 0x7FFFu + ((u >> 16) & 1u)) >> 16);
}
__device__ __forceinline__ float bf2f(unsigned short h) {
  union { unsigned u; float f; } c; c.u = ((unsigned)h) << 16;
  return c.f;
}
// HW packed f32->bf16 (RNE, identical to f2bf emulation). T12 primitive.
__device__ __forceinline__ unsigned cvtpk(float lo, float hi) {
  unsigned r;
  asm("v_cvt_pk_bf16_f32 %0, %1, %2" : "=v"(r) : "v"(lo), "v"(hi));
  return r;
}

// async global->LDS, 16 bytes per lane. LDS dest must be wave-uniform + lane*16.
__device__ __forceinline__ void gload16(const unsigned short* g, unsigned short* l) {
  __builtin_amdgcn_global_load_lds(
      (const __attribute__((address_space(1))) unsigned int*)g,
      (__attribute__((address_space(3))) unsigned int*)l, 16, 0, 0);
}

// ---------------------------------------------------------------------------
// f32 -> bf16 cast; y selects input (0 = a, 1 = x).
// ---------------------------------------------------------------------------
__global__ void cast_bf16_kernel(const float* __restrict__ a, const float* __restrict__ x,
                                 unsigned short* __restrict__ outa,
                                 unsigned short* __restrict__ outx) {
  const float* in = blockIdx.y ? x : a;
  unsigned short* out = blockIdx.y ? outx : outa;
  int i = blockIdx.x * blockDim.x + threadIdx.x;
  const float4* p = (const float4*)in + (size_t)i * 2;
  float4 v0 = p[0], v1 = p[1];
  short8v o;
  o[0] = (short)f2bf(v0.x); o[1] = (short)f2bf(v0.y);
  o[2] = (short)f2bf(v0.z); o[3] = (short)f2bf(v0.w);
  o[4] = (short)f2bf(v1.x); o[5] = (short)f2bf(v1.y);
  o[6] = (short)f2bf(v1.z); o[7] = (short)f2bf(v1.w);
  *((short8v*)out + i) = o;
}

// ---------------------------------------------------------------------------
// W (512 x C) f32 -> Wt (C x 512) bf16; z in 0..5 selects the weight.
// z == 6: fill RoPE cos/sin table (identical float exprs to the original).
// ---------------------------------------------------------------------------
__global__ void wtrans_kernel(const float* __restrict__ w0, const float* __restrict__ w1,
                              const float* __restrict__ w2, const float* __restrict__ w3,
                              const float* __restrict__ w4, const float* __restrict__ w5,
                              unsigned short* __restrict__ o0, unsigned short* __restrict__ o1,
                              unsigned short* __restrict__ o2, unsigned short* __restrict__ o3,
                              unsigned short* __restrict__ o4, unsigned short* __restrict__ o5,
                              float* __restrict__ rtab) {
  __shared__ float T[32][33];
  const int z = blockIdx.z;
  if (z == 6) {
    const int flat = blockIdx.y * 16 + blockIdx.x;       // 0..255
    const int base = (flat * 256 + threadIdx.x) * 8;     // covers 524288
    const float LOG1E4 = 9.210340371976184f;
    #pragma unroll
    for (int k = 0; k < 8; k++) {
      int e = base + k;
      int pos = e >> 6, c = e & 63, jj = c & 31;
      float inv = __expf(-((float)jj / 32.f) * LOG1E4);
      float sn, cs;
      sincosf((float)pos * inv, &sn, &cs);
      rtab[e] = (c < 32) ? cs : sn;
    }
    return;
  }
  const float* in; unsigned short* out; int C;
  switch (z) {
    case 0: in = w0; out = o0; C = 512; break;
    case 1: in = w1; out = o1; C = 128; break;
    case 2: in = w2; out = o2; C = 128; break;
    case 3: in = w3; out = o3; C = 512; break;
    case 4: in = w4; out = o4; C = 128; break;
    default: in = w5; out = o5; C = 128; break;
  }
  const int c0 = blockIdx.x * 32, k0 = blockIdx.y * 32;
  if (c0 >= C) return;
  const int tx = threadIdx.x & 31, ty = threadIdx.x >> 5;
  #pragma unroll
  for (int i = 0; i < 4; i++)
    T[ty + i * 8][tx] = in[(size_t)(k0 + ty + i * 8) * C + c0 + tx];
  __syncthreads();
  #pragma unroll
  for (int i = 0; i < 4; i++)
    out[(size_t)(c0 + ty + i * 8) * 512 + k0 + tx] = f2bf(T[tx][ty + i * 8]);
}

// ---------------------------------------------------------------------------
// Merged MFMA projection v3: 128-row x 64-col block, double-buffered
// global_load_lds staging, XOR-granule swizzle, BK=64, 8 k-steps.
// grid (64, 12, 2).
// ---------------------------------------------------------------------------
__global__ __launch_bounds__(256, 3) void proj_all_kernel(
    const unsigned short* __restrict__ Xa, const unsigned short* __restrict__ Xx,
    const unsigned short* __restrict__ WtQa, const unsigned short* __restrict__ WtKa,
    const unsigned short* __restrict__ WtVa, const unsigned short* __restrict__ WtQx,
    const unsigned short* __restrict__ WtKx, const unsigned short* __restrict__ WtVx,
    const float* __restrict__ gq_a, const float* __restrict__ gk_a,
    const float* __restrict__ gq_x, const float* __restrict__ gk_x,
    const float* __restrict__ Rtab,
    unsigned short* __restrict__ Qb, unsigned short* __restrict__ Kb,
    unsigned short* __restrict__ Kt, unsigned short* __restrict__ Vt)
{
  __shared__ __attribute__((aligned(16))) unsigned short Xs[2][128][64];  // 32 KB
  __shared__ __attribute__((aligned(16))) unsigned short Ws2[2][64][64];  // 16 KB
  unsigned short (*Tsh)[72] = (unsigned short (*)[72])&Xs[0][0][0];       // alias

  const int tid = threadIdx.x;
  const int w = tid >> 6, l = tid & 63, lc = l & 15, lg = l >> 4;
  const int r7 = lc & 7;
  const int z = blockIdx.z;
  const int y = blockIdx.y;
  const int row0 = blockIdx.x * 128;
  const int pos_offset = z ? 4096 : 0;

  const unsigned short* Xbf = z ? Xx : Xa;
  const unsigned short* Wt;
  const float* gamma = nullptr;
  unsigned short* OUT = nullptr;
  unsigned short* OUTT = nullptr;
  int h, Hout, doNR;
  if (y < 8) {
    h = y; Hout = NH; doNR = 1;
    Wt = z ? WtQx : WtQa; gamma = z ? gq_x : gq_a; OUT = Qb;
  } else if (y < 10) {
    h = y - 8; Hout = NKV; doNR = 1;
    Wt = z ? WtKx : WtKa; gamma = z ? gk_x : gk_a; OUT = Kb; OUTT = Kt;
  } else {
    h = y - 10; Hout = NKV; doNR = 0;
    Wt = z ? WtVx : WtVa; OUTT = Vt;
  }

  const int srow = tid >> 3;
  const int sg   = (tid & 7) ^ (srow & 7);
  const unsigned short* Xrow = Xbf + (size_t)(row0 + srow) * 512 + sg * 8;
  const unsigned short* Wrow = Wt + (size_t)(h * 64 + srow) * 512 + sg * 8;

  f32x4 acc[2][4];
  #pragma unroll
  for (int m = 0; m < 2; m++)
    #pragma unroll
    for (int ct = 0; ct < 4; ct++) { acc[m][ct][0]=0.f; acc[m][ct][1]=0.f; acc[m][ct][2]=0.f; acc[m][ct][3]=0.f; }

  // ---- prologue: stage k-step 0 into buf 0 ----
  #pragma unroll
  for (int p = 0; p < 4; p++)
    gload16(Xrow + (size_t)p * 32 * 512, &Xs[0][0][0] + p * 2048 + tid * 8);
  #pragma unroll
  for (int p = 0; p < 2; p++)
    gload16(Wrow + (size_t)p * 32 * 512, &Ws2[0][0][0] + p * 2048 + tid * 8);
  __syncthreads();

  for (int s = 0; s < 8; s++) {
    const int buf = s & 1;
    if (s < 7) {
      const int k0n = (s + 1) * 64;
      #pragma unroll
      for (int p = 0; p < 4; p++)
        gload16(Xrow + (size_t)p * 32 * 512 + k0n, &Xs[buf ^ 1][0][0] + p * 2048 + tid * 8);
      #pragma unroll
      for (int p = 0; p < 2; p++)
        gload16(Wrow + (size_t)p * 32 * 512 + k0n, &Ws2[buf ^ 1][0][0] + p * 2048 + tid * 8);
    }

    __builtin_amdgcn_s_setprio(1);
    #pragma unroll
    for (int kc = 0; kc < 2; kc++) {
      const int gsw = (((kc * 4 + lg) ^ r7) & 7) * 8;
      short8v a8[2], b8[4];
      #pragma unroll
      for (int m = 0; m < 2; m++)
        a8[m] = *(const short8v*)&Xs[buf][m * 64 + w * 16 + lc][gsw];
      #pragma unroll
      for (int ct = 0; ct < 4; ct++)
        b8[ct] = *(const short8v*)&Ws2[buf][ct * 16 + lc][gsw];
      #pragma unroll
      for (int m = 0; m < 2; m++)
        #pragma unroll
        for (int ct = 0; ct < 4; ct++)
          acc[m][ct] = MFMA16(a8[m], b8[ct], acc[m][ct], 0, 0, 0);
    }
    __builtin_amdgcn_s_setprio(0);
    __syncthreads();
  }

  // ---- epilogue ----
  float gam[4];
  if (doNR) {
    #pragma unroll
    for (int ct = 0; ct < 4; ct++) gam[ct] = gamma[h * 64 + ct * 16 + lc];
  }

  #pragma unroll
  for (int m = 0; m < 2; m++) {
    if (doNR) {
      float srw[4];
      #pragma unroll
      for (int reg = 0; reg < 4; reg++) {
        float ss = acc[m][0][reg]*acc[m][0][reg] + acc[m][1][reg]*acc[m][1][reg]
                 + acc[m][2][reg]*acc[m][2][reg] + acc[m][3][reg]*acc[m][3][reg];
        ss += __shfl_xor(ss, 1, 64);
        ss += __shfl_xor(ss, 2, 64);
        ss += __shfl_xor(ss, 4, 64);
        ss += __shfl_xor(ss, 8, 64);
        srw[reg] = 8.0f / fmaxf(sqrtf(ss), 1e-12f);
      }
      const int posb = pos_offset + ((row0 + m * 64) & 4095) + w * 16 + lg * 4;
      #pragma unroll
      for (int reg = 0; reg < 4; reg++) {
        const float* tabr = Rtab + (size_t)(posb + reg) * 64;
        #pragma unroll
        for (int half = 0; half < 2; half++) {
          float cs = tabr[half * 16 + lc];
          float sn = tabr[32 + half * 16 + lc];
          float v1 = acc[m][half][reg] * srw[reg] * gam[half];
          float v2 = acc[m][half + 2][reg] * srw[reg] * gam[half + 2];
          acc[m][half][reg]     = v1 * cs - v2 * sn;
          acc[m][half + 2][reg] = v2 * cs + v1 * sn;
        }
      }
    }

    #pragma unroll
    for (int ct = 0; ct < 4; ct++)
      #pragma unroll
      for (int reg = 0; reg < 4; reg++)
        Tsh[w * 16 + lg * 4 + reg][ct * 16 + lc] = f2bf(acc[m][ct][reg]);
    __syncthreads();

    const int growm = row0 + m * 64;
    const int b = growm >> 12;
    const int pos0 = pos_offset + (growm & 4095);
    if (OUT) {
      const int r = tid >> 2, part = tid & 3;
      unsigned short* dst = OUT + (((size_t)b * Hout + h) * NTOK + pos0 + r) * 64 + part * 16;
      short8v u0 = *(const short8v*)&Tsh[r][part * 16];
      short8v u1 = *(const short8v*)&Tsh[r][part * 16 + 8];
      *(short8v*)dst = u0;
      *(short8v*)(dst + 8) = u1;
    }
    if (OUTT) {
      const int e = tid >> 2, part = tid & 3;
      short8v t0, t1;
      #pragma unroll
      for (int jj = 0; jj < 16; jj++) {
        const int LG = ((part & 1) << 1) | (jj >> 3);
        const int H  = (jj >> 2) & 1;
        const int I  = jj & 3;
        const int srcrow = (part >> 1) * 32 + H * 16 + LG * 4 + I;
        unsigned short v = Tsh[srcrow][e];
        if (jj < 8) t0[jj] = (short)v; else t1[jj - 8] = (short)v;
      }
      unsigned short* dstT = OUTT + (((size_t)b * NKV + h) * 64 + e) * NTOK + pos0 + part * 16;
      *(short8v*)dstT = t0;
      *(short8v*)(dstT + 8) = t1;
    }
    __syncthreads();
  }
}

// ---------------------------------------------------------------------------
// Per-segment partial summaries (8 n-chunks of 128 tokens) via MFMA.
// grid 256 = (bkv*8+seg)*8+chunk.
// ---------------------------------------------------------------------------
__global__ __launch_bounds__(256) void seg_summary_kernel(
    const unsigned short* __restrict__ Kt, const unsigned short* __restrict__ Vt,
    float* __restrict__ Spart, float* __restrict__ Zpart)
{
  const int blk = blockIdx.x;
  const int chunk = blk & 7;
  const int seg = (blk >> 3) & 7;
  const int bkv = blk >> 6;
  const int tid = threadIdx.x;
  const int w = tid >> 6, l = tid & 63, lc = l & 15, lg = l >> 4;
  const unsigned short* KtB = Kt + ((size_t)bkv * 64) * NTOK + seg * SEGL + chunk * 128;
  const unsigned short* VtB = Vt + ((size_t)bkv * 64) * NTOK + seg * SEGL + chunk * 128;

  f32x4 acc[4];
  #pragma unroll
  for (int ct = 0; ct < 4; ct++) { acc[ct][0]=0.f; acc[ct][1]=0.f; acc[ct][2]=0.f; acc[ct][3]=0.f; }
  float zacc[4] = {0.f, 0.f, 0.f, 0.f};

  for (int n0 = 0; n0 < 128; n0 += 32) {
    short8v av = *(const short8v*)(VtB + (size_t)(w * 16 + lc) * NTOK + n0 + lg * 8);
    #pragma unroll
    for (int ct = 0; ct < 4; ct++) {
      short8v kv = *(const short8v*)(KtB + (size_t)(ct * 16 + lc) * NTOK + n0 + lg * 8);
      short8v skv;
      float zp = 0.f;
      #pragma unroll
      for (int i = 0; i < 8; i++) {
        float kf = bf2f((unsigned short)kv[i]);
        float sk = kf > 0.f ? kf + 1.f : __expf(kf);
        zp += sk;
        skv[i] = (short)f2bf(sk);
      }
      zacc[ct] += zp;
      acc[ct] = MFMA16(av, skv, acc[ct], 0, 0, 0);
    }
  }

  float* Sp = Spart + (size_t)blk * 4096;
  #pragma unroll
  for (int ct = 0; ct < 4; ct++)
    #pragma unroll
    for (int reg = 0; reg < 4; reg++)
      Sp[(size_t)(w * 16 + lg * 4 + reg) * 64 + ct * 16 + lc] = acc[ct][reg];

  if (w == 0) {
    #pragma unroll
    for (int ct = 0; ct < 4; ct++) {
      zacc[ct] += __shfl_xor(zacc[ct], 16, 64);
      zacc[ct] += __shfl_xor(zacc[ct], 32, 64);
    }
    if (lg == 0) {
      float* Zp = Zpart + (size_t)blk * 64;
      #pragma unroll
      for (int ct = 0; ct < 4; ct++) Zp[ct * 16 + lc] = zacc[ct];
    }
  }
}

// Chunk-reduce + exclusive prefix over segments -> bf16 PT + f32 PZ.
__global__ void prefix_kernel(const float* __restrict__ Spart, const float* __restrict__ Zpart,
                              unsigned short* __restrict__ PT, float* __restrict__ PZ)
{
  const int bkv = blockIdx.x;
  const int col = blockIdx.y * 256 + threadIdx.x;
  float run = 0.f;
  for (int s = 0; s < NSEG; s++) {
    float v = 0.f;
    #pragma unroll
    for (int c = 0; c < 8; c++)
      v += Spart[(((size_t)(bkv * 8 + s)) * 8 + c) * 4096 + col];
    PT[((size_t)bkv * 8 + s) * 4096 + col] = f2bf(run);
    run += v;
  }
  if (blockIdx.y == 0 && threadIdx.x < 64) {
    const int d = threadIdx.x;
    float rz = 0.f;
    for (int s = 0; s < NSEG; s++) {
      float v = 0.f;
      #pragma unroll
      for (int c = 0; c < 8; c++)
        v += Zpart[(((size_t)(bkv * 8 + s)) * 8 + c) * 64 + d];
      PZ[((size_t)bkv * 8 + s) * 64 + d] = rz;
      rz += v;
    }
  }
}

// ---------------------------------------------------------------------------
// MFMA flash attention v7 (best verified: 68.5 us): 2 heads/block share staged
// K/V, R9-proven staging schedule, hoisted per-step K/V fragment reads,
// v_cvt_pk_bf16_f32 packing, XCD-bijective swizzle. Grid 512, 256 threads.
// ---------------------------------------------------------------------------
__global__ __launch_bounds__(256, 2) void attn_mfma_kernel(
    const unsigned short* __restrict__ Qb, const unsigned short* __restrict__ Kb,
    const unsigned short* __restrict__ Vt, const unsigned short* __restrict__ PT,
    const float* __restrict__ PZ, const float* __restrict__ beta,
    float* __restrict__ OUT)
{
  __shared__ __attribute__((aligned(16))) unsigned short Ks[2][64][64];
  __shared__ __attribute__((aligned(16))) unsigned short Vs[2][64][64];
  const int tid = threadIdx.x;
  const int w = tid >> 6;
  const int l = tid & 63;
  const int lc = l & 15;
  const int lg = l >> 4;
  const int r7 = lc & 7;

  // XCD-aware bijective swizzle (512 blocks, 512 % 8 == 0)
  const int bid = (blockIdx.x & 7) * 64 + (blockIdx.x >> 3);
  const int j   = bid & 7;
  const int seg = (bid >> 3) & 7;
  const int pp  = (bid >> 6) & 1;
  const int kv  = (bid >> 7) & 1;
  const int b   = bid >> 8;
  const int bkv = b * NKV + kv;          // jnp.tile -> h % KVH
  const int qtA = 15 - j, qtB = j;
  const int segbase = seg * SEGL;

  const unsigned short* Kbase = Kb + ((size_t)bkv * NTOK + segbase) * 64;
  const unsigned short* Vbase = Vt + ((size_t)bkv * 64) * NTOK + segbase;

  // staging constants: identical to proven R9 schedule
  const int srow = tid >> 3;                 // 0..31
  const int sg   = (tid & 7) ^ (srow & 7);   // involution granule swizzle

  // Q fragments: [hh][tt]
  short8v aq0[2][2], aq1[2][2];
  #pragma unroll
  for (int hh = 0; hh < 2; hh++) {
    const int h = kv + 4 * pp + 2 * hh;
    const int bh = b * NH + h;
    {
      const unsigned short* qp =
          Qb + (((size_t)bh * NTOK) + segbase + qtA * 64 + w * 16 + lc) * 64 + lg * 8;
      aq0[hh][0] = *(const short8v*)(qp);
      aq1[hh][0] = *(const short8v*)(qp + 32);
    }
    {
      const unsigned short* qp =
          Qb + (((size_t)bh * NTOK) + segbase + qtB * 64 + w * 16 + lc) * 64 + lg * 8;
      aq0[hh][1] = *(const short8v*)(qp);
      aq1[hh][1] = *(const short8v*)(qp + 32);
    }
  }

  f32x4 O[2][2][4];
  #pragma unroll
  for (int hh = 0; hh < 2; hh++)
    #pragma unroll
    for (int tt = 0; tt < 2; tt++)
      #pragma unroll
      for (int ce = 0; ce < 4; ce++) { O[hh][tt][ce][0]=0.f; O[hh][tt][ce][1]=0.f; O[hh][tt][ce][2]=0.f; O[hh][tt][ce][3]=0.f; }
  float rsumL[2][2] = {{0.f, 0.f}, {0.f, 0.f}};

  // exp(s*0.125 - 8) == exp2(s*c1 - c2)
  const float c1 = 0.125f * 1.44269504089f;
  const float c2 = 8.0f * 1.44269504089f;

  // ---- prologue: stage tile 0 (R9-exact) ----
  {
    unsigned short* kD = &Ks[0][0][0];
    unsigned short* vD = &Vs[0][0][0];
    #pragma unroll
    for (int p = 0; p < 2; p++) {
      const int row = p * 32 + srow;
      gload16(Kbase + (size_t)row * 64 + sg * 8, kD + p * 2048 + tid * 8);
      gload16(Vbase + (size_t)row * NTOK + sg * 8, vD + p * 2048 + tid * 8);
    }
  }
  __syncthreads();

  for (int kt = 0; kt <= qtA; ++kt) {
    const int buf = kt & 1;
    if (kt < qtA) {
      const int ktn = kt + 1;
      unsigned short* kD = &Ks[buf ^ 1][0][0];
      unsigned short* vD = &Vs[buf ^ 1][0][0];
      #pragma unroll
      for (int p = 0; p < 2; p++) {
        const int row = p * 32 + srow;
        gload16(Kbase + (size_t)(ktn * 64 + row) * 64 + sg * 8, kD + p * 2048 + tid * 8);
        gload16(Vbase + (size_t)row * NTOK + ktn * 64 + sg * 8, vD + p * 2048 + tid * 8);
      }
    }

    __builtin_amdgcn_s_setprio(1);

    // ---- hoisted per-step K/V fragment reads (shared by both heads/tiles) ----
    short8v ak0r[4], ak1r[4];
    #pragma unroll
    for (int ck = 0; ck < 4; ck++) {
      const int krow = ck * 16 + lc;
      ak0r[ck] = *(const short8v*)&Ks[buf][krow][((lg ^ r7) & 7) * 8];
      ak1r[ck] = *(const short8v*)&Ks[buf][krow][(((lg + 4) ^ r7) & 7) * 8];
    }
    short8v bvr[2][4];
    #pragma unroll
    for (int cp = 0; cp < 2; cp++)
      #pragma unroll
      for (int ce = 0; ce < 4; ce++)
        bvr[cp][ce] = *(const short8v*)&Vs[buf][ce * 16 + lc][(((cp * 4 + lg) ^ r7) & 7) * 8];

    #pragma unroll
    for (int hh = 0; hh < 2; hh++) {
      #pragma unroll
      for (int tt = 0; tt < 2; tt++) {
        if (tt == 1 && kt > qtB) continue;
        const int qt_ = tt ? qtB : qtA;
        const bool diag = (kt == qt_);
        const int ctmax = diag ? w : 3;

        // ---- S^T = K Q^T, P = exp2(s*c1 - c2) with causal mask ----
        unsigned paw[4][2];
        #pragma unroll
        for (int ck = 0; ck < 4; ck++) {
          if (ck > ctmax) { paw[ck][0] = 0u; paw[ck][1] = 0u; continue; }
          f32x4 s;
          s[0]=0.f; s[1]=0.f; s[2]=0.f; s[3]=0.f;
          s = MFMA16(ak0r[ck], aq0[hh][tt], s, 0, 0, 0);
          s = MFMA16(ak1r[ck], aq1[hh][tt], s, 0, 0, 0);
          const bool needmask = diag && (ck == w);
          float p0 = exp2f(s[0] * c1 - c2);
          float p1 = exp2f(s[1] * c1 - c2);
          float p2 = exp2f(s[2] * c1 - c2);
          float p3 = exp2f(s[3] * c1 - c2);
          if (needmask) {
            if (lg * 4 + 0 > lc) p0 = 0.f;
            if (lg * 4 + 1 > lc) p1 = 0.f;
            if (lg * 4 + 2 > lc) p2 = 0.f;
            if (lg * 4 + 3 > lc) p3 = 0.f;
          }
          rsumL[hh][tt] += p0 + p1 + p2 + p3;
          paw[ck][0] = cvtpk(p0, p1);
          paw[ck][1] = cvtpk(p2, p3);
        }

        // ---- O += P V via 16x16x32; A from packed words, B from registers ----
        #pragma unroll
        for (int cp = 0; cp < 2; cp++) {
          if (cp * 2 > ctmax) continue;
          int4v a8i;
          a8i[0] = (int)paw[cp * 2][0];
          a8i[1] = (int)paw[cp * 2][1];
          a8i[2] = (int)paw[cp * 2 + 1][0];
          a8i[3] = (int)paw[cp * 2 + 1][1];
          short8v a8;
          __builtin_memcpy(&a8, &a8i, 16);
          #pragma unroll
          for (int ce = 0; ce < 4; ce++)
            O[hh][tt][ce] = MFMA16(a8, bvr[cp][ce], O[hh][tt][ce], 0, 0, 0);
        }
      }
    }
    __builtin_amdgcn_s_setprio(0);
    __syncthreads();
  }

  // ---- epilogue per (head, tile): softmax sum + memory path + gated write ----
  const unsigned short* stp = PT + ((size_t)bkv * NSEG + seg) * 4096 + lc * 64 + lg * 8;
  const float* zp = PZ + ((size_t)bkv * NSEG + seg) * 64 + lg * 8;

  #pragma unroll
  for (int hh = 0; hh < 2; hh++) {
    const int h = kv + 4 * pp + 2 * hh;
    const float g = 1.f / (1.f + __expf(-beta[h]));
    const float g1 = 1.f - g;

    #pragma unroll
    for (int tt = 0; tt < 2; tt++) {
      float rsum = rsumL[hh][tt];
      rsum += __shfl_xor(rsum, 16, 64);
      rsum += __shfl_xor(rsum, 32, 64);

      float sq0[8], sq1[8];
      float den = 1e-12f;
      #pragma unroll
      for (int i = 0; i < 8; i++) {
        float f0 = bf2f((unsigned short)aq0[hh][tt][i]);
        sq0[i] = f0 > 0.f ? f0 + 1.f : __expf(f0);
        den += sq0[i] * zp[i];
        float f1 = bf2f((unsigned short)aq1[hh][tt][i]);
        sq1[i] = f1 > 0.f ? f1 + 1.f : __expf(f1);
        den += sq1[i] * zp[32 + i];
      }
      int4v q0i, q1i;
      q0i[0] = (int)cvtpk(sq0[0], sq0[1]);
      q0i[1] = (int)cvtpk(sq0[2], sq0[3]);
      q0i[2] = (int)cvtpk(sq0[4], sq0[5]);
      q0i[3] = (int)cvtpk(sq0[6], sq0[7]);
      q1i[0] = (int)cvtpk(sq1[0], sq1[1]);
      q1i[1] = (int)cvtpk(sq1[2], sq1[3]);
      q1i[2] = (int)cvtpk(sq1[4], sq1[5]);
      q1i[3] = (int)cvtpk(sq1[6], sq1[7]);
      short8v asq0, asq1;
      __builtin_memcpy(&asq0, &q0i, 16);
      __builtin_memcpy(&asq1, &q1i, 16);

      f32x4 N[4];
      #pragma unroll
      for (int ct = 0; ct < 4; ct++) { N[ct][0]=0.f; N[ct][1]=0.f; N[ct][2]=0.f; N[ct][3]=0.f; }
      #pragma unroll
      for (int ct = 0; ct < 4; ct++) {
        short8v bs0 = *(const short8v*)(stp + ct * 16 * 64);
        short8v bs1 = *(const short8v*)(stp + ct * 16 * 64 + 32);
        N[ct] = MFMA16(asq0, bs0, N[ct], 0, 0, 0);
        N[ct] = MFMA16(asq1, bs1, N[ct], 0, 0, 0);
      }
      den += __shfl_xor(den, 16, 64);
      den += __shfl_xor(den, 32, 64);
      float denc[4], rs[4];
      #pragma unroll
      for (int reg = 0; reg < 4; reg++) {
        denc[reg] = __shfl(den, lg * 4 + reg, 64);
        rs[reg]   = __shfl(rsum, lg * 4 + reg, 64);
      }

      const int q0 = (tt ? qtB : qtA) * 64;
      const int nrow = segbase + q0 + w * 16 + lg * 4;
      #pragma unroll
      for (int reg = 0; reg < 4; reg++) {
        const int n = nrow + reg;
        const float invs = 1.f / rs[reg];
        const float invd = 1.f / denc[reg];
        size_t obase;
        if (n < 4096) obase = (size_t)BATCH * 4096 * 512 + (((size_t)b * 4096 + n) * NH + h) * 64;
        else          obase = (((size_t)b * 4096 + (n - 4096)) * NH + h) * 64;
        #pragma unroll
        for (int ce = 0; ce < 4; ce++) {
          OUT[obase + ce * 16 + lc] = g * N[ce][reg] * invd + g1 * O[hh][tt][ce][reg] * invs;
        }
      }
    }
  }
}

// ---------------------------------------------------------------------------
extern "C" void kernel_launch(void* const* d_in, const int* in_sizes, int n_in,
                              void* d_out, int out_size, void* d_ws, size_t ws_size,
                              hipStream_t stream) {
  const float* x    = (const float*)d_in[0];
  const float* a    = (const float*)d_in[1];
  const float* Wq_x = (const float*)d_in[2];
  const float* Wk_x = (const float*)d_in[3];
  const float* Wv_x = (const float*)d_in[4];
  const float* Wq_a = (const float*)d_in[5];
  const float* Wk_a = (const float*)d_in[6];
  const float* Wv_a = (const float*)d_in[7];
  const float* gq_x = (const float*)d_in[8];
  const float* gk_x = (const float*)d_in[9];
  const float* gq_a = (const float*)d_in[10];
  const float* gk_a = (const float*)d_in[11];
  const float* beta = (const float*)d_in[12];

  unsigned short* Qb = (unsigned short*)d_ws;          // 8388608
  unsigned short* Kb = Qb + (size_t)8388608;           // 2097152
  unsigned short* Kt = Kb + (size_t)2097152;           // 2097152 (permuted)
  unsigned short* Vt = Kt + (size_t)2097152;           // 2097152 (permuted)
  unsigned short* Xa = Vt + (size_t)2097152;           // 4194304
  unsigned short* Xx = Xa + (size_t)4194304;           // 4194304
  unsigned short* WtQa = Xx + (size_t)4194304;         // 262144
  unsigned short* WtKa = WtQa + (size_t)262144;        // 65536
  unsigned short* WtVa = WtKa + (size_t)65536;         // 65536
  unsigned short* WtQx = WtVa + (size_t)65536;         // 262144
  unsigned short* WtKx = WtQx + (size_t)262144;        // 65536
  unsigned short* WtVx = WtKx + (size_t)65536;         // 65536
  float* Spart = (float*)(WtVx + (size_t)65536);       // 1048576 f32 (4 MB)
  float* Zpart = Spart + (size_t)1048576;              // 16384
  float* PZ = Zpart + (size_t)16384;                   // 2048
  unsigned short* PT = (unsigned short*)(PZ + (size_t)2048); // 131072 bf16
  float* Rtab = (float*)(PT + (size_t)131072);         // 524288 f32 (2 MB)

  cast_bf16_kernel<<<dim3(2048, 2), 256, 0, stream>>>(a, x, Xa, Xx);
  wtrans_kernel<<<dim3(16, 16, 7), 256, 0, stream>>>(
      Wq_a, Wk_a, Wv_a, Wq_x, Wk_x, Wv_x, WtQa, WtKa, WtVa, WtQx, WtKx, WtVx, Rtab);
  proj_all_kernel<<<dim3(64, 12, 2), 256, 0, stream>>>(
      Xa, Xx, WtQa, WtKa, WtVa, WtQx, WtKx, WtVx,
      gq_a, gk_a, gq_x, gk_x, Rtab, Qb, Kb, Kt, Vt);
  seg_summary_kernel<<<256, 256, 0, stream>>>(Kt, Vt, Spart, Zpart);
  prefix_kernel<<<dim3(4, 16), 256, 0, stream>>>(Spart, Zpart, PT, PZ);
  attn_mfma_kernel<<<dim3(512), 256, 0, stream>>>(Qb, Kb, Vt, PT, PZ, beta, (float*)d_out);
}